// Round 1
// baseline (188.800 us; speedup 1.0000x reference)
//
#include <hip/hip_runtime.h>
#include <math.h>

#define BB 256
#define NN 196
#define DD 768
#define TD 32

// Kernel 1: per-batch argmax/softmax-max over axis=1 (position classes) and
// winner scatter (later j wins -> max j per slot).
__global__ __launch_bounds__(256) void pos_conf_kernel(
    const float* __restrict__ logits,  // [B,N,N]
    float* __restrict__ conf_out,      // [B,N] (tail of d_out)
    int* __restrict__ winner_out)      // [B,N] in workspace
{
    const int b = blockIdx.x;
    const int t = threadIdx.x;

    __shared__ int winner_s[NN];
    if (t < NN) winner_s[t] = -1;
    __syncthreads();

    if (t < NN) {
        const float* col = logits + (size_t)b * NN * NN + t;
        float m = -INFINITY;
        float s = 0.0f;
        int idx = 0;
        for (int i = 0; i < NN; ++i) {
            float x = col[(size_t)i * NN];   // row i is contiguous across lanes
            if (x > m) {
                // online softmax rescale; first iter: expf(-inf)=0 -> s=1
                s = s * expf(m - x) + 1.0f;
                m = x;
                idx = i;                      // strict > keeps first occurrence
            } else {
                s += expf(x - m);
            }
        }
        conf_out[b * NN + t] = 1.0f / s;     // max of softmax over axis=1
        atomicMax(&winner_s[idx], t);        // winner[p] = max j with pos[j]==p
    }
    __syncthreads();
    if (t < NN) winner_out[b * NN + t] = winner_s[t];
}

// Kernel 2: gather rows by winner, 3-tap smooth over patch index (reading
// pre-smoothed originals), write transposed [B, D, N] (= [B, D, g, g]).
__global__ __launch_bounds__(256) void rearrange_kernel(
    const float* __restrict__ features,  // [B,N,D]
    const int* __restrict__ winner,      // [B,N]
    float* __restrict__ img)             // [B,D,N]
{
    const int b  = blockIdx.y;
    const int d0 = blockIdx.x * TD;
    const int t  = threadIdx.x;

    __shared__ float tile[NN][TD + 1];   // +1 pad: bank = (p + d) % 32, conflict-free
    __shared__ int winner_s[NN];

    if (t < NN) winner_s[t] = winner[b * NN + t];
    __syncthreads();

    // Load gathered rows: 8 rows x 32 d-lanes per iteration (128 B contiguous/row).
    const int d  = t & (TD - 1);
    const int r0 = t >> 5;               // 0..7
    for (int r = r0; r < NN; r += 8) {
        const int w = winner_s[r];
        float v = 0.0f;
        if (w >= 0) v = features[(size_t)b * NN * DD + (size_t)w * DD + d0 + d];
        tile[r][d] = v;
    }
    __syncthreads();

    // Write: for each d, 196 lanes store one contiguous row of the output image.
    if (t < NN) {
        const int p = t;
        const size_t base = (size_t)b * DD * NN + (size_t)d0 * NN + p;
        for (int dd = 0; dd < TD; ++dd) {
            float v;
            if (p == 0)            v = tile[0][dd];
            else if (p == NN - 1)  v = tile[NN - 1][dd];
            else                   v = (tile[p - 1][dd] + tile[p][dd] + tile[p + 1][dd]) * (1.0f / 3.0f);
            img[base + (size_t)dd * NN] = v;
        }
    }
}

extern "C" void kernel_launch(void* const* d_in, const int* in_sizes, int n_in,
                              void* d_out, int out_size, void* d_ws, size_t ws_size,
                              hipStream_t stream) {
    const float* features = (const float*)d_in[0];
    const float* logits   = (const float*)d_in[1];

    float* out  = (float*)d_out;
    float* img  = out;                              // B*D*N floats
    float* conf = out + (size_t)BB * DD * NN;       // B*N floats
    int*   winner = (int*)d_ws;                     // B*N ints

    pos_conf_kernel<<<BB, 256, 0, stream>>>(logits, conf, winner);

    dim3 grid(DD / TD, BB);
    rearrange_kernel<<<grid, 256, 0, stream>>>(features, winner, img);
}

// Round 2
// 95.878 us; speedup vs baseline: 1.9692x; 1.9692x over previous
//
#include <hip/hip_runtime.h>
#include <math.h>

#define BB 256
#define NN 196
#define DD 768
#define TDK 32
#define PSTRIDE 204   // tile row stride in floats: 816 B, 16B-aligned, bank-friendly

// Kernel 1: per-batch argmax + max-softmax over axis=1, 4-way row-split for TLP.
// 1024 threads: group g = t>>8 handles rows [49g, 49g+49), lane jj = t&255 owns column jj.
__global__ __launch_bounds__(1024) void pos_conf_kernel(
    const float* __restrict__ logits,  // [B,N,N]
    float* __restrict__ conf_out,      // [B,N]
    int* __restrict__ winner_out)      // [B,N]
{
    const int b  = blockIdx.x;
    const int t  = threadIdx.x;
    const int g  = t >> 8;
    const int jj = t & 255;

    __shared__ float sm[4][256];
    __shared__ float ss[4][256];
    __shared__ int   si[4][256];
    __shared__ int   winner_s[256];

    if (t < NN) winner_s[t] = -1;

    if (jj < NN) {
        const float* col = logits + (size_t)b * NN * NN + jj;
        float m = -INFINITY, s = 0.0f;
        int idx = 0;
        const int i0 = 49 * g;
        for (int i = i0; i < i0 + 49; ++i) {
            float x = col[(size_t)i * NN];
            if (x > m) {                     // strict > keeps first occurrence
                s = s * expf(m - x) + 1.0f;  // first iter: expf(-inf)=0
                m = x;
                idx = i;
            } else {
                s += expf(x - m);
            }
        }
        sm[g][jj] = m; ss[g][jj] = s; si[g][jj] = idx;
    }
    __syncthreads();

    if (t < NN) {
        const int j = t;
        float m = -INFINITY;
        int idx = 0;
        for (int gg = 0; gg < 4; ++gg) {     // ascending: earliest chunk wins ties
            float mg = sm[gg][j];
            if (mg > m) { m = mg; idx = si[gg][j]; }
        }
        float s = 0.0f;
        for (int gg = 0; gg < 4; ++gg)
            s += ss[gg][j] * expf(sm[gg][j] - m);
        conf_out[b * NN + j] = 1.0f / s;
        atomicMax(&winner_s[idx], j);        // winner[p] = max j with pos[j]==p
    }
    __syncthreads();
    if (t < NN) winner_out[b * NN + t] = winner_s[t];
}

// Kernel 2: gather rows by winner, 3-tap smooth along p, write [B, D, N].
// LDS tile stored transposed: tile[d][p], so the store phase reads contiguous p.
__global__ __launch_bounds__(256) void rearrange_kernel(
    const float* __restrict__ features,  // [B,N,D]
    const int* __restrict__ winner,      // [B,N]
    float* __restrict__ img)             // [B,D,N]
{
    const int b  = blockIdx.y;
    const int d0 = blockIdx.x * TDK;
    const int t  = threadIdx.x;

    __shared__ float tile[TDK][PSTRIDE];   // tile[d][p]

    const float* fb = features + (size_t)b * NN * DD;
    const int* wb = winner + b * NN;

    // Load: thread (r = t>>3, d4 = t&7) loads float4 = 4 d's of gathered row r.
    const int d4 = (t & 7) * 4;
    #pragma unroll
    for (int i = 0; i < 7; ++i) {
        const int r = (t >> 3) + 32 * i;
        if (r < NN) {
            const int w = wb[r];
            float4 v = make_float4(0.f, 0.f, 0.f, 0.f);
            if (w >= 0)
                v = *reinterpret_cast<const float4*>(fb + (size_t)w * DD + d0 + d4);
            tile[d4 + 0][r] = v.x;
            tile[d4 + 1][r] = v.y;
            tile[d4 + 2][r] = v.z;
            tile[d4 + 3][r] = v.w;
        }
    }
    __syncthreads();

    // Store: item q -> (d = q/49, c = q%49); writes img[b][d0+d][4c..4c+3].
    // Store address = base + q*16B: fully contiguous float4 stores per wave.
    #pragma unroll
    for (int it = 0; it < 7; ++it) {
        const int q = t + 256 * it;
        if (q < TDK * 49) {
            const int d = q / 49;
            const int c = q - 49 * d;
            const int p0 = 4 * c;
            const float4 ctr = *reinterpret_cast<const float4*>(&tile[d][p0]);  // 16B-aligned
            const float left  = tile[d][p0 > 0 ? p0 - 1 : 0];
            const float right = tile[d][p0 + 4 < NN ? p0 + 4 : NN - 1];
            float4 o;
            o.x = (p0 == 0)          ? ctr.x : (left  + ctr.x + ctr.y) * (1.0f / 3.0f);
            o.y = (ctr.x + ctr.y + ctr.z) * (1.0f / 3.0f);
            o.z = (ctr.y + ctr.z + ctr.w) * (1.0f / 3.0f);
            o.w = (p0 + 3 == NN - 1) ? ctr.w : (ctr.z + ctr.w + right) * (1.0f / 3.0f);
            float* dst = img + (size_t)b * DD * NN + (size_t)(d0 + d) * NN + p0;
            *reinterpret_cast<float4*>(dst) = o;
        }
    }
}

extern "C" void kernel_launch(void* const* d_in, const int* in_sizes, int n_in,
                              void* d_out, int out_size, void* d_ws, size_t ws_size,
                              hipStream_t stream) {
    const float* features = (const float*)d_in[0];
    const float* logits   = (const float*)d_in[1];

    float* out  = (float*)d_out;
    float* img  = out;                              // B*D*N floats
    float* conf = out + (size_t)BB * DD * NN;       // B*N floats
    int*   winner = (int*)d_ws;                     // B*N ints

    pos_conf_kernel<<<BB, 1024, 0, stream>>>(logits, conf, winner);

    dim3 grid(DD / TDK, BB);
    rearrange_kernel<<<grid, 256, 0, stream>>>(features, winner, img);
}

// Round 3
// 52.961 us; speedup vs baseline: 3.5649x; 1.8104x over previous
//
#include <hip/hip_runtime.h>
#include <math.h>

#define BB 256
#define NN 196
#define DD 768
#define TDK 32
#define PSTRIDE 204   // tile row stride in floats: 816 B, 16B-aligned

typedef float f32x4 __attribute__((ext_vector_type(4)));

// Kernel 1: per-batch argmax + max-softmax over axis=1, 4-way row-split.
// 1024 threads: group g = t>>8 handles rows [49g, 49g+49), lane jj = t&255 owns column jj.
__global__ __launch_bounds__(1024) void pos_conf_kernel(
    const float* __restrict__ logits,  // [B,N,N]
    float* __restrict__ conf_out,      // [B,N]
    int* __restrict__ winner_out)      // [B,N]
{
    const int b  = blockIdx.x;
    const int t  = threadIdx.x;
    const int g  = t >> 8;
    const int jj = t & 255;

    __shared__ float sm[4][256];
    __shared__ float ss[4][256];
    __shared__ int   si[4][256];
    __shared__ int   winner_s[256];

    if (t < NN) winner_s[t] = -1;

    if (jj < NN) {
        const float* col = logits + (size_t)b * NN * NN + (size_t)(49 * g) * NN + jj;
        float m = -INFINITY, s = 0.0f;
        int idx = 0;
        const int i0 = 49 * g;
        #pragma unroll 7
        for (int i = 0; i < 49; ++i) {
            const float x = col[(size_t)i * NN];
            const float mn = fmaxf(m, x);
            idx = (x > m) ? (i0 + i) : idx;          // strict >: first occurrence
            s = s * __expf(m - mn) + __expf(x - mn); // branchless online softmax
            m = mn;
        }
        sm[g][jj] = m; ss[g][jj] = s; si[g][jj] = idx;
    }
    __syncthreads();

    if (t < NN) {
        const int j = t;
        float m = -INFINITY;
        int idx = 0;
        #pragma unroll
        for (int gg = 0; gg < 4; ++gg) {     // ascending: earliest chunk wins ties
            const float mg = sm[gg][j];
            if (mg > m) { m = mg; idx = si[gg][j]; }
        }
        float s = 0.0f;
        #pragma unroll
        for (int gg = 0; gg < 4; ++gg)
            s += ss[gg][j] * __expf(sm[gg][j] - m);
        conf_out[b * NN + j] = 1.0f / s;
        atomicMax(&winner_s[idx], j);        // winner[p] = max j with pos[j]==p
    }
    __syncthreads();
    if (t < NN) winner_out[b * NN + t] = winner_s[t];
}

// Kernel 2: gather rows by winner, 3-tap smooth along p, write [B, D, N].
// LDS tile stored transposed: tile[d][p], so the store phase reads contiguous p.
__global__ __launch_bounds__(256) void rearrange_kernel(
    const float* __restrict__ features,  // [B,N,D]
    const int* __restrict__ winner,      // [B,N]
    float* __restrict__ img)             // [B,D,N]
{
    const int b  = blockIdx.y;
    const int d0 = blockIdx.x * TDK;
    const int t  = threadIdx.x;

    __shared__ float tile[TDK][PSTRIDE];   // tile[d][p]

    const float* fb = features + (size_t)b * NN * DD;
    const int* wb = winner + b * NN;

    // Prefetch winner indices (breaks the dependent load->load chain).
    int w[7];
    #pragma unroll
    for (int i = 0; i < 7; ++i) {
        const int r = (t >> 3) + 32 * i;
        w[i] = (r < NN) ? wb[r] : -1;
    }

    // Load: thread (r = t>>3, d4 = (t&7)*4) loads float4 = 4 d's of gathered row r.
    const int d4 = (t & 7) * 4;
    #pragma unroll
    for (int i = 0; i < 7; ++i) {
        const int r = (t >> 3) + 32 * i;
        if (r < NN) {
            float4 v = make_float4(0.f, 0.f, 0.f, 0.f);
            if (w[i] >= 0)
                v = *reinterpret_cast<const float4*>(fb + (size_t)w[i] * DD + d0 + d4);
            tile[d4 + 0][r] = v.x;
            tile[d4 + 1][r] = v.y;
            tile[d4 + 2][r] = v.z;
            tile[d4 + 3][r] = v.w;
        }
    }
    __syncthreads();

    // Store: item q -> (d = q/49, c = q%49); writes img[b][d0+d][4c..4c+3].
    // Store address = base + q*16B: fully contiguous nontemporal float4 stores.
    #pragma unroll
    for (int it = 0; it < 7; ++it) {
        const int q = t + 256 * it;
        if (q < TDK * 49) {
            const int d = q / 49;
            const int c = q - 49 * d;
            const int p0 = 4 * c;
            const float4 ctr = *reinterpret_cast<const float4*>(&tile[d][p0]);  // 16B-aligned
            const float left  = tile[d][p0 > 0 ? p0 - 1 : 0];
            const float right = tile[d][p0 + 4 < NN ? p0 + 4 : NN - 1];
            f32x4 o;
            o.x = (p0 == 0)          ? ctr.x : (left  + ctr.x + ctr.y) * (1.0f / 3.0f);
            o.y = (ctr.x + ctr.y + ctr.z) * (1.0f / 3.0f);
            o.z = (ctr.y + ctr.z + ctr.w) * (1.0f / 3.0f);
            o.w = (p0 + 3 == NN - 1) ? ctr.w : (ctr.z + ctr.w + right) * (1.0f / 3.0f);
            float* dst = img + (size_t)b * DD * NN + (size_t)(d0 + d) * NN + p0;
            __builtin_nontemporal_store(o, reinterpret_cast<f32x4*>(dst));
        }
    }
}

extern "C" void kernel_launch(void* const* d_in, const int* in_sizes, int n_in,
                              void* d_out, int out_size, void* d_ws, size_t ws_size,
                              hipStream_t stream) {
    const float* features = (const float*)d_in[0];
    const float* logits   = (const float*)d_in[1];

    float* out  = (float*)d_out;
    float* img  = out;                              // B*D*N floats
    float* conf = out + (size_t)BB * DD * NN;       // B*N floats
    int*   winner = (int*)d_ws;                     // B*N ints

    pos_conf_kernel<<<BB, 1024, 0, stream>>>(logits, conf, winner);

    dim3 grid(DD / TDK, BB);
    rearrange_kernel<<<grid, 256, 0, stream>>>(features, winner, img);
}